// Round 1
// baseline (243.797 us; speedup 1.0000x reference)
//
#include <hip/hip_runtime.h>

using bf16 = __bf16;
typedef __bf16 bf16x8 __attribute__((ext_vector_type(8)));
typedef __bf16 bf16x4 __attribute__((ext_vector_type(4)));
typedef float  f32x4  __attribute__((ext_vector_type(4)));

#define MFMA16(a, b, c) __builtin_amdgcn_mfma_f32_16x16x32_bf16((a), (b), (c), 0, 0, 0)

static constexpr int S = 2048, E = 1024;

// ---------------- fp32 -> bf16 elementwise ----------------
__global__ __launch_bounds__(256) void k_cvt(const float* __restrict__ in, bf16* __restrict__ out, int n) {
    int i = (blockIdx.x * 256 + threadIdx.x) * 4;
    if (i >= n) return;
    float4 v = *(const float4*)(in + i);
    bf16x4 o = { (bf16)v.x, (bf16)v.y, (bf16)v.z, (bf16)v.w };
    *(bf16x4*)(out + i) = o;
}

// ---------------- transpose+convert: in [K][N] f32 -> out [N][K] bf16 ----------------
__global__ __launch_bounds__(256) void k_tcvt(const float* __restrict__ in, bf16* __restrict__ out, int K, int N) {
    __shared__ float tile[32][33];
    int bx = blockIdx.x * 32;  // N
    int by = blockIdx.y * 32;  // K
    int tx = threadIdx.x & 31, ty = threadIdx.x >> 5;
#pragma unroll
    for (int i = 0; i < 32; i += 8)
        tile[ty + i][tx] = in[(long)(by + ty + i) * N + bx + tx];
    __syncthreads();
#pragma unroll
    for (int i = 0; i < 32; i += 8)
        out[(long)(bx + ty + i) * K + by + tx] = (bf16)tile[tx][ty + i];
}

// ---------------- bf16 GEMM, B transposed: C[M][N] = A[M][K] * Bt[N][K]^T + bias ----------------
template <bool OUT_F32>
__global__ __launch_bounds__(256) void k_gemm_bt(const bf16* __restrict__ A, const bf16* __restrict__ Bt,
                                                 const float* __restrict__ bias, void* __restrict__ Cout,
                                                 int Mm, int Nn, int Kk) {
    const int bm = blockIdx.x * 128;
    const int bn = blockIdx.y * 128;
    const int tid = threadIdx.x;
    const int w = tid >> 6, lane = tid & 63;
    const int wm = (w >> 1) * 64, wn = (w & 1) * 64;
    const int col = lane & 15, quad = lane >> 4;

    __shared__ bf16 sA[128 * 40];  // stride 40 elems (80B) -> conflict-free b128 frag reads
    __shared__ bf16 sB[128 * 40];

    f32x4 acc[4][4] = {};

    for (int k0 = 0; k0 < Kk; k0 += 32) {
        __syncthreads();
#pragma unroll
        for (int i = 0; i < 2; i++) {
            int v = tid + i * 256;
            int row = v >> 2, q8 = (v & 3) * 8;
            *(bf16x8*)(sA + row * 40 + q8) = *(const bf16x8*)(A + (long)(bm + row) * Kk + k0 + q8);
            *(bf16x8*)(sB + row * 40 + q8) = *(const bf16x8*)(Bt + (long)(bn + row) * Kk + k0 + q8);
        }
        __syncthreads();
        bf16x8 af[4], bfr[4];
#pragma unroll
        for (int mt = 0; mt < 4; mt++) af[mt] = *(const bf16x8*)(sA + (wm + mt * 16 + col) * 40 + quad * 8);
#pragma unroll
        for (int nt = 0; nt < 4; nt++) bfr[nt] = *(const bf16x8*)(sB + (wn + nt * 16 + col) * 40 + quad * 8);
#pragma unroll
        for (int mt = 0; mt < 4; mt++)
#pragma unroll
            for (int nt = 0; nt < 4; nt++)
                acc[mt][nt] = MFMA16(af[mt], bfr[nt], acc[mt][nt]);
    }

#pragma unroll
    for (int mt = 0; mt < 4; mt++) {
        const int gr = bm + wm + mt * 16 + quad * 4;
#pragma unroll
        for (int nt = 0; nt < 4; nt++) {
            const int gc = bn + wn + nt * 16 + col;
            const float bv = bias[gc];
#pragma unroll
            for (int r = 0; r < 4; r++) {
                float vv = acc[mt][nt][r] + bv;
                if (OUT_F32) ((float*)Cout)[(long)(gr + r) * Nn + gc] = vv;
                else         ((bf16*)Cout)[(long)(gr + r) * Nn + gc] = (bf16)vv;
            }
        }
    }
}

// ---------------- causal flash attention ----------------
// qkv: [B*S][3E] bf16 (Q at col h*64, K at E+h*64, V at 2E+h*64); out: [B*S][E] bf16.
// QT=64 (1 m-tile / wave), KT=64. Block handles q-tile pair (p, 31-p) -> uniform work.
__global__ __launch_bounds__(256) void k_attn(const bf16* __restrict__ qkv, bf16* __restrict__ out) {
    const int p = blockIdx.x;   // 0..15
    const int bh = blockIdx.y;  // 0..31
    const int b = bh >> 4, h = bh & 15;
    const int tid = threadIdx.x;
    const int w = tid >> 6, lane = tid & 63;
    const int col = lane & 15, quad = lane >> 4;

    __shared__ bf16 sK[64 * 72];
    __shared__ bf16 sVt[64 * 72];
    __shared__ bf16 sP[4][16 * 72];

    const long base = (long)b * S * 3072;
    const int qo = h * 64, ko = E + h * 64, vo = 2 * E + h * 64;
    const float cscale = 0.125f * 1.44269504088896340736f;  // 1/sqrt(64) * log2(e)

#pragma unroll 1
    for (int sel = 0; sel < 2; sel++) {
        const int qt = sel ? 31 - p : p;
        const int q0 = qt * 64;

        bf16x8 aq0, aq1;
        {
            const bf16* qp = qkv + base + (long)(q0 + w * 16 + col) * 3072 + qo + quad * 8;
            aq0 = *(const bf16x8*)(qp);
            aq1 = *(const bf16x8*)(qp + 32);
        }
        f32x4 o0 = {}, o1 = {}, o2 = {}, o3 = {};
        float mrow[4], lrow[4];
#pragma unroll
        for (int r = 0; r < 4; r++) { mrow[r] = -1e30f; lrow[r] = 0.f; }

#pragma unroll 1
        for (int kt = 0; kt <= qt; kt++) {
            const int k0 = kt * 64;
            __syncthreads();
            // stage K tile [64][64] -> sK (stride 72)
#pragma unroll
            for (int i = 0; i < 2; i++) {
                int v = tid + i * 256;
                int row = v >> 3, q8 = (v & 7) * 8;
                *(bf16x8*)(sK + row * 72 + q8) =
                    *(const bf16x8*)(qkv + base + (long)(k0 + row) * 3072 + ko + q8);
            }
            // stage V transposed: sVt[d][kk] = V[k0+kk][d], via 2x2 register transpose
#pragma unroll
            for (int i = 0; i < 4; i++) {
                int t2 = tid + i * 256;
                int d0 = (t2 & 31) * 2, kk0 = (t2 >> 5) * 2;
                const bf16* vp = qkv + base + (long)(k0 + kk0) * 3072 + vo + d0;
                unsigned a0 = *(const unsigned*)(vp);
                unsigned a1 = *(const unsigned*)(vp + 3072);
                *(unsigned*)(sVt + d0 * 72 + kk0)       = (a0 & 0xffffu) | (a1 << 16);
                *(unsigned*)(sVt + (d0 + 1) * 72 + kk0) = (a0 >> 16) | (a1 & 0xffff0000u);
            }
            __syncthreads();

            // S = Q K^T (per wave: 1 m-tile x 4 n-tiles, k=64 in 2 steps)
            f32x4 s[4];
#pragma unroll
            for (int nt = 0; nt < 4; nt++) {
                const bf16* kp = sK + (nt * 16 + col) * 72 + quad * 8;
                f32x4 z = {};
                z = MFMA16(aq0, *(const bf16x8*)(kp), z);
                z = MFMA16(aq1, *(const bf16x8*)(kp + 32), z);
                s[nt] = z;
            }
            // scale + causal mask + chunk row-max
            const int qrow = q0 + w * 16 + quad * 4;  // + r
            float chmax[4] = { -1e30f, -1e30f, -1e30f, -1e30f };
#pragma unroll
            for (int nt = 0; nt < 4; nt++) {
                const int kc = k0 + nt * 16 + col;
#pragma unroll
                for (int r = 0; r < 4; r++) {
                    float sv = s[nt][r] * cscale;
                    if (kc > qrow + r) sv = -1e30f;  // only fires on the diagonal tile
                    s[nt][r] = sv;
                    chmax[r] = fmaxf(chmax[r], sv);
                }
            }
            // online softmax (row lives across the 16 lanes of a quad)
            float alpha[4];
#pragma unroll
            for (int r = 0; r < 4; r++) {
                float m2 = chmax[r];
                m2 = fmaxf(m2, __shfl_xor(m2, 1));
                m2 = fmaxf(m2, __shfl_xor(m2, 2));
                m2 = fmaxf(m2, __shfl_xor(m2, 4));
                m2 = fmaxf(m2, __shfl_xor(m2, 8));
                const float mnew = fmaxf(mrow[r], m2);
                alpha[r] = exp2f(mrow[r] - mnew);
                mrow[r] = mnew;
                float rs = 0.f;
#pragma unroll
                for (int nt = 0; nt < 4; nt++) {
                    float pe = exp2f(s[nt][r] - mnew);
                    s[nt][r] = pe;
                    rs += pe;
                }
                rs += __shfl_xor(rs, 1);
                rs += __shfl_xor(rs, 2);
                rs += __shfl_xor(rs, 4);
                rs += __shfl_xor(rs, 8);
                lrow[r] = lrow[r] * alpha[r] + rs;
            }
#pragma unroll
            for (int r = 0; r < 4; r++) { o0[r] *= alpha[r]; o1[r] *= alpha[r]; o2[r] *= alpha[r]; o3[r] *= alpha[r]; }
            // P (C-layout) -> LDS (A-layout source)
            bf16* pw = sP[w];
#pragma unroll
            for (int nt = 0; nt < 4; nt++)
#pragma unroll
                for (int r = 0; r < 4; r++)
                    pw[(quad * 4 + r) * 72 + nt * 16 + col] = (bf16)s[nt][r];
            __syncthreads();
            // O += P V  (k=64 in 2 steps; b-frags from transposed V)
#pragma unroll
            for (int ks = 0; ks < 2; ks++) {
                bf16x8 ap = *(const bf16x8*)(pw + col * 72 + ks * 32 + quad * 8);
                const bf16* vb = sVt + col * 72 + ks * 32 + quad * 8;
                o0 = MFMA16(ap, *(const bf16x8*)(vb),           o0);
                o1 = MFMA16(ap, *(const bf16x8*)(vb + 16 * 72), o1);
                o2 = MFMA16(ap, *(const bf16x8*)(vb + 32 * 72), o2);
                o3 = MFMA16(ap, *(const bf16x8*)(vb + 48 * 72), o3);
            }
        }
        // epilogue: O /= l, write bf16
#pragma unroll
        for (int r = 0; r < 4; r++) {
            const float li = 1.f / lrow[r];
            bf16* op = out + (long)(b * S + q0 + w * 16 + quad * 4 + r) * E + h * 64 + col;
            op[0]  = (bf16)(o0[r] * li);
            op[16] = (bf16)(o1[r] * li);
            op[32] = (bf16)(o2[r] * li);
            op[48] = (bf16)(o3[r] * li);
        }
    }
}

extern "C" void kernel_launch(void* const* d_in, const int* in_sizes, int n_in,
                              void* d_out, int out_size, void* d_ws, size_t ws_size,
                              hipStream_t stream) {
    const float* hs = (const float*)d_in[0];   // [2,2048,1024]
    const float* w0 = (const float*)d_in[1];   // [1024,3072]
    const float* b0 = (const float*)d_in[2];   // [3072]
    const float* w1 = (const float*)d_in[3];   // [1024,1024]
    const float* b1 = (const float*)d_in[4];   // [1024]
    float* outp = (float*)d_out;               // [2,2048,1024] fp32

    char* ws = (char*)d_ws;
    bf16* A0   = (bf16*)(ws);                   // 4096*1024 bf16 = 8 MB
    bf16* Wt0  = (bf16*)(ws + 8388608);         // 3072*1024 = 6 MB
    bf16* Wt1  = (bf16*)(ws + 14680064);        // 1024*1024 = 2 MB
    bf16* qkv  = (bf16*)(ws + 16777216);        // 4096*3072 = 24 MB
    bf16* attn = (bf16*)(ws + 41943040);        // 4096*1024 = 8 MB

    k_cvt<<<4096, 256, 0, stream>>>(hs, A0, 4194304);
    k_tcvt<<<dim3(96, 32), 256, 0, stream>>>(w0, Wt0, 1024, 3072);
    k_tcvt<<<dim3(32, 32), 256, 0, stream>>>(w1, Wt1, 1024, 1024);
    k_gemm_bt<false><<<dim3(32, 24), 256, 0, stream>>>(A0, Wt0, b0, qkv, 4096, 3072, 1024);
    k_attn<<<dim3(16, 32), 256, 0, stream>>>(qkv, attn);
    k_gemm_bt<true><<<dim3(32, 8), 256, 0, stream>>>(attn, Wt1, b1, outp, 4096, 1024, 1024);
}

// Round 2
// 227.791 us; speedup vs baseline: 1.0703x; 1.0703x over previous
//
#include <hip/hip_runtime.h>

using bf16 = __bf16;
typedef __bf16 bf16x8 __attribute__((ext_vector_type(8)));
typedef __bf16 bf16x4 __attribute__((ext_vector_type(4)));
typedef float  f32x4  __attribute__((ext_vector_type(4)));

#define MFMA16(a, b, c) __builtin_amdgcn_mfma_f32_16x16x32_bf16((a), (b), (c), 0, 0, 0)

static constexpr int S = 2048, E = 1024;
static constexpr float CSCALE = 0.18033688011112042f;  // 1/sqrt(64) * log2(e)

__device__ __forceinline__ void gld16(const bf16* g, bf16* l) {
    __builtin_amdgcn_global_load_lds((const __attribute__((address_space(1))) unsigned*)g,
                                     (__attribute__((address_space(3))) unsigned*)l, 16, 0, 0);
}

// ---------------- fp32 -> bf16 elementwise ----------------
__global__ __launch_bounds__(256) void k_cvt(const float* __restrict__ in, bf16* __restrict__ out, int n) {
    int i = (blockIdx.x * 256 + threadIdx.x) * 4;
    if (i >= n) return;
    float4 v = *(const float4*)(in + i);
    bf16x4 o = { (bf16)v.x, (bf16)v.y, (bf16)v.z, (bf16)v.w };
    *(bf16x4*)(out + i) = o;
}

// ---------------- transpose+convert: in [K][N] f32 -> out [N][K] bf16 ----------------
__global__ __launch_bounds__(256) void k_tcvt(const float* __restrict__ in, bf16* __restrict__ out, int K, int N) {
    __shared__ float tile[32][33];
    int bx = blockIdx.x * 32;  // N
    int by = blockIdx.y * 32;  // K
    int tx = threadIdx.x & 31, ty = threadIdx.x >> 5;
#pragma unroll
    for (int i = 0; i < 32; i += 8)
        tile[ty + i][tx] = in[(long)(by + ty + i) * N + bx + tx];
    __syncthreads();
#pragma unroll
    for (int i = 0; i < 32; i += 8)
        out[(long)(bx + ty + i) * K + by + tx] = (bf16)tile[tx][ty + i];
}

// ---------------- bf16 GEMM (m97-style global_load_lds staging) ----------------
// C[M][N] = A[M][K] * Bt[N][K]^T + bias; cols < scale_cols get *scale after bias.
template <bool OUT_F32>
__global__ __launch_bounds__(256) void k_gemm_bt(const bf16* __restrict__ A, const bf16* __restrict__ Bt,
                                                 const float* __restrict__ bias, void* __restrict__ Cout,
                                                 int Mm, int Nn, int Kk, int scale_cols, float scale) {
    const int bm = blockIdx.x * 128;
    const int bn = blockIdx.y * 128;
    const int tid = threadIdx.x;
    const int w = tid >> 6, lane = tid & 63;
    const int wm = (w >> 1) * 64, wn = (w & 1) * 64;
    const int col = lane & 15, quad = lane >> 4;

    __shared__ bf16 sA[128 * 32];  // unpadded: required by global_load_lds contiguity
    __shared__ bf16 sB[128 * 32];

    // staging: chunk c = w*128 + j*64 + lane; row = c>>2, s = c&3 (4x 16B chunks per 32-elem row)
    const int c0 = w * 128 + lane;
    const int r0 = c0 >> 2, s0 = c0 & 3;
    const int r1 = (c0 + 64) >> 2, s1 = (c0 + 64) & 3;
    const bf16* pA0 = A + (long)(bm + r0) * Kk + s0 * 8;
    const bf16* pA1 = A + (long)(bm + r1) * Kk + s1 * 8;
    const bf16* pB0 = Bt + (long)(bn + r0) * Kk + s0 * 8;
    const bf16* pB1 = Bt + (long)(bn + r1) * Kk + s1 * 8;
    bf16* lA0 = sA + w * 1024;        // wave-uniform LDS bases; data lands at base + lane*16B
    bf16* lA1 = sA + w * 1024 + 512;
    bf16* lB0 = sB + w * 1024;
    bf16* lB1 = sB + w * 1024 + 512;

    f32x4 acc[4][4] = {};

    for (int k0 = 0; k0 < Kk; k0 += 32) {
        __syncthreads();
        gld16(pA0 + k0, lA0);
        gld16(pA1 + k0, lA1);
        gld16(pB0 + k0, lB0);
        gld16(pB1 + k0, lB1);
        __syncthreads();
        bf16x8 af[4], bfr[4];
#pragma unroll
        for (int mt = 0; mt < 4; mt++) af[mt] = *(const bf16x8*)(sA + (wm + mt * 16 + col) * 32 + quad * 8);
#pragma unroll
        for (int nt = 0; nt < 4; nt++) bfr[nt] = *(const bf16x8*)(sB + (wn + nt * 16 + col) * 32 + quad * 8);
#pragma unroll
        for (int mt = 0; mt < 4; mt++)
#pragma unroll
            for (int nt = 0; nt < 4; nt++)
                acc[mt][nt] = MFMA16(af[mt], bfr[nt], acc[mt][nt]);
    }

#pragma unroll
    for (int mt = 0; mt < 4; mt++) {
        const int gr = bm + wm + mt * 16 + quad * 4;
#pragma unroll
        for (int nt = 0; nt < 4; nt++) {
            const int gc = bn + wn + nt * 16 + col;
            const float bv = bias[gc];
            const float sc = (gc < scale_cols) ? scale : 1.0f;
#pragma unroll
            for (int r = 0; r < 4; r++) {
                float vv = (acc[mt][nt][r] + bv) * sc;
                if (OUT_F32) ((float*)Cout)[(long)(gr + r) * Nn + gc] = vv;
                else         ((bf16*)Cout)[(long)(gr + r) * Nn + gc] = (bf16)vv;
            }
        }
    }
}

// ---------------- causal flash attention ----------------
// qkv: [B*S][3E] bf16, Q pre-scaled by CSCALE. 512-thread blocks: waves 0-3 take the
// long q-tile (31-p), waves 4-7 the short one (p); shared K/V staging; uniform-ish work.
__global__ __launch_bounds__(512) void k_attn(const bf16* __restrict__ qkv, bf16* __restrict__ out) {
    const int p = blockIdx.x;   // 0..15
    const int bh = blockIdx.y;  // 0..31
    const int b = bh >> 4, h = bh & 15;
    const int tid = threadIdx.x;
    const int w = tid >> 6, lane = tid & 63;
    const int grp = w >> 2, wsub = w & 3;
    const int col = lane & 15, quad = lane >> 4;

    const int qt = grp ? p : 31 - p;
    const int q0 = qt * 64;
    const int ktmax = 31 - p;

    __shared__ bf16 sK[64 * 72];
    __shared__ bf16 sVt[64 * 80];   // stride 80: aligned b128 frag reads, conflict-free writes
    __shared__ bf16 sP[8][16 * 72];

    const long base = (long)b * S * 3072;
    const int ko = E + h * 64, vo = 2 * E + h * 64;

    bf16x8 aq0, aq1;
    {
        const bf16* qp = qkv + base + (long)(q0 + wsub * 16 + col) * 3072 + h * 64 + quad * 8;
        aq0 = *(const bf16x8*)(qp);
        aq1 = *(const bf16x8*)(qp + 32);
    }
    f32x4 o0 = {}, o1 = {}, o2 = {}, o3 = {};
    float mrow[4], lrow[4];
#pragma unroll
    for (int r = 0; r < 4; r++) { mrow[r] = -1e30f; lrow[r] = 0.f; }

#pragma unroll 1
    for (int kt = 0; kt <= ktmax; kt++) {
        const int k0 = kt * 64;
        __syncthreads();
        // stage K tile [64][64] -> sK (stride 72): 512 threads x 8 elems, coalesced b128
        {
            const int row = tid >> 3, q8 = (tid & 7) * 8;
            *(bf16x8*)(sK + row * 72 + q8) =
                *(const bf16x8*)(qkv + base + (long)(k0 + row) * 3072 + ko + q8);
        }
        // stage V transposed: sVt[d][kk] = V[k0+kk][d]. Lane-consecutive kk -> conflict-free writes.
        {
            const int kk0 = (tid & 31) * 2, d0 = (tid >> 5) * 4;
            const bf16* vp = qkv + base + (long)(k0 + kk0) * 3072 + vo + d0;
            ushort4 va = *(const ushort4*)(vp);
            ushort4 vb2 = *(const ushort4*)(vp + 3072);
            *(unsigned*)(sVt + (d0 + 0) * 80 + kk0) = (unsigned)va.x | ((unsigned)vb2.x << 16);
            *(unsigned*)(sVt + (d0 + 1) * 80 + kk0) = (unsigned)va.y | ((unsigned)vb2.y << 16);
            *(unsigned*)(sVt + (d0 + 2) * 80 + kk0) = (unsigned)va.z | ((unsigned)vb2.z << 16);
            *(unsigned*)(sVt + (d0 + 3) * 80 + kk0) = (unsigned)va.w | ((unsigned)vb2.w << 16);
        }
        __syncthreads();

        if (kt <= qt) {
            // S = Q K^T (scores already in log2 units: Q pre-scaled)
            f32x4 s[4];
#pragma unroll
            for (int nt = 0; nt < 4; nt++) {
                const bf16* kp = sK + (nt * 16 + col) * 72 + quad * 8;
                f32x4 z = {};
                z = MFMA16(aq0, *(const bf16x8*)(kp), z);
                z = MFMA16(aq1, *(const bf16x8*)(kp + 32), z);
                s[nt] = z;
            }
            float chmax[4] = { -1e30f, -1e30f, -1e30f, -1e30f };
            if (kt == qt) {  // diagonal tile: apply causal mask
                const int qrow = q0 + wsub * 16 + quad * 4;
#pragma unroll
                for (int nt = 0; nt < 4; nt++) {
                    const int kc = k0 + nt * 16 + col;
#pragma unroll
                    for (int r = 0; r < 4; r++) {
                        float sv = (kc > qrow + r) ? -1e30f : s[nt][r];
                        s[nt][r] = sv;
                        chmax[r] = fmaxf(chmax[r], sv);
                    }
                }
            } else {
#pragma unroll
                for (int nt = 0; nt < 4; nt++)
#pragma unroll
                    for (int r = 0; r < 4; r++)
                        chmax[r] = fmaxf(chmax[r], s[nt][r]);
            }
            // online softmax (row spread across 16 lanes of a quad)
            float alpha[4];
#pragma unroll
            for (int r = 0; r < 4; r++) {
                float m2 = chmax[r];
                m2 = fmaxf(m2, __shfl_xor(m2, 1));
                m2 = fmaxf(m2, __shfl_xor(m2, 2));
                m2 = fmaxf(m2, __shfl_xor(m2, 4));
                m2 = fmaxf(m2, __shfl_xor(m2, 8));
                const float mnew = fmaxf(mrow[r], m2);
                alpha[r] = __builtin_amdgcn_exp2f(mrow[r] - mnew);
                mrow[r] = mnew;
                float rs = 0.f;
#pragma unroll
                for (int nt = 0; nt < 4; nt++) {
                    float pe = __builtin_amdgcn_exp2f(s[nt][r] - mnew);
                    s[nt][r] = pe;
                    rs += pe;
                }
                rs += __shfl_xor(rs, 1);
                rs += __shfl_xor(rs, 2);
                rs += __shfl_xor(rs, 4);
                rs += __shfl_xor(rs, 8);
                lrow[r] = lrow[r] * alpha[r] + rs;
            }
#pragma unroll
            for (int r = 0; r < 4; r++) { o0[r] *= alpha[r]; o1[r] *= alpha[r]; o2[r] *= alpha[r]; o3[r] *= alpha[r]; }
            // P (C-layout) -> LDS; wave-private, no block barrier needed
            bf16* pw = sP[w];
#pragma unroll
            for (int nt = 0; nt < 4; nt++)
#pragma unroll
                for (int r = 0; r < 4; r++)
                    pw[(quad * 4 + r) * 72 + nt * 16 + col] = (bf16)s[nt][r];
            // O += P V
#pragma unroll
            for (int ks = 0; ks < 2; ks++) {
                bf16x8 ap = *(const bf16x8*)(pw + col * 72 + ks * 32 + quad * 8);
                const bf16* vb = sVt + col * 80 + ks * 32 + quad * 8;
                o0 = MFMA16(ap, *(const bf16x8*)(vb),           o0);
                o1 = MFMA16(ap, *(const bf16x8*)(vb + 16 * 80), o1);
                o2 = MFMA16(ap, *(const bf16x8*)(vb + 32 * 80), o2);
                o3 = MFMA16(ap, *(const bf16x8*)(vb + 48 * 80), o3);
            }
        }
    }
    // epilogue: O /= l, write bf16
#pragma unroll
    for (int r = 0; r < 4; r++) {
        const float li = 1.f / lrow[r];
        bf16* op = out + (long)(b * S + q0 + wsub * 16 + quad * 4 + r) * E + h * 64 + col;
        op[0]  = (bf16)(o0[r] * li);
        op[16] = (bf16)(o1[r] * li);
        op[32] = (bf16)(o2[r] * li);
        op[48] = (bf16)(o3[r] * li);
    }
}

extern "C" void kernel_launch(void* const* d_in, const int* in_sizes, int n_in,
                              void* d_out, int out_size, void* d_ws, size_t ws_size,
                              hipStream_t stream) {
    const float* hs = (const float*)d_in[0];   // [2,2048,1024]
    const float* w0 = (const float*)d_in[1];   // [1024,3072]
    const float* b0 = (const float*)d_in[2];   // [3072]
    const float* w1 = (const float*)d_in[3];   // [1024,1024]
    const float* b1 = (const float*)d_in[4];   // [1024]
    float* outp = (float*)d_out;               // [2,2048,1024] fp32

    char* ws = (char*)d_ws;
    bf16* A0   = (bf16*)(ws);                   // 4096*1024 bf16 = 8 MB
    bf16* Wt0  = (bf16*)(ws + 8388608);         // 3072*1024 = 6 MB
    bf16* Wt1  = (bf16*)(ws + 14680064);        // 1024*1024 = 2 MB
    bf16* qkv  = (bf16*)(ws + 16777216);        // 4096*3072 = 24 MB
    bf16* attn = (bf16*)(ws + 41943040);        // 4096*1024 = 8 MB

    k_cvt<<<4096, 256, 0, stream>>>(hs, A0, 4194304);
    k_tcvt<<<dim3(96, 32), 256, 0, stream>>>(w0, Wt0, 1024, 3072);
    k_tcvt<<<dim3(32, 32), 256, 0, stream>>>(w1, Wt1, 1024, 1024);
    // QKV GEMM: pre-scale Q columns (gc < 1024) by 1/sqrt(D)*log2(e)
    k_gemm_bt<false><<<dim3(32, 24), 256, 0, stream>>>(A0, Wt0, b0, qkv, 4096, 3072, 1024, 1024, CSCALE);
    k_attn<<<dim3(16, 32), 512, 0, stream>>>(qkv, attn);
    k_gemm_bt<true><<<dim3(32, 8), 256, 0, stream>>>(attn, Wt1, b1, outp, 4096, 1024, 1024, 0, 1.0f);
}